// Round 14
// baseline (145.668 us; speedup 1.0000x reference)
//
#include <hip/hip_runtime.h>
#include <math.h>

#define BB 16
#define NN 24564
#define CC 81
#define KK 50
#define MT 200
#define NROWS (BB * NN)
#define RB 192                 // row-blocks per batch: ceil(24564/128)
#define CAND_CAP 512           // class c>0: ~123+-11 (35 sigma); class 0: ~389+-20 (6 sigma)
#define T1 0.995f              // tier-1 threshold, classes 1..80
#define T1C0 0.975f            // tier-1 threshold, class 0 (masked-column yield is lower)
#define TIER_W 0.02f
#define PADI 32                // ints per counter slot (128B padding)
#define CHUNK 128              // k_nms box-staging chunk

typedef unsigned long long u64;
typedef unsigned int u32;

__device__ __forceinline__ u64 pack_cand(float s, int n) {
    return ((u64)__float_as_uint(s) << 32) | (u32)(~(u32)n);
}

// descending bitonic sort of P u64 keys in LDS, NT threads
template <int P, int NT>
__device__ __forceinline__ void bitonic_desc(u64* a, int tid) {
    for (int k = 2; k <= P; k <<= 1) {
        for (int j = k >> 1; j > 0; j >>= 1) {
            for (int i = tid; i < P; i += NT) {
                int l = i ^ j;
                if (l > i) {
                    u64 x = a[i], y = a[l];
                    bool sw = (i & k) ? (x > y) : (x < y);
                    if (sw) { a[i] = y; a[l] = x; }
                }
            }
            __syncthreads();
        }
    }
}

// ---------------------------------------------------------------------------
// Kernel 0: zero the 1296 used counter slots.
// ---------------------------------------------------------------------------
__global__ __launch_bounds__(256) void k_zero(int* __restrict__ cnt_g)
{
    int i = blockIdx.x * 256 + threadIdx.x;
    if (i < BB * CC) cnt_g[i * PADI] = 0;
}

// ---------------------------------------------------------------------------
// Kernel 1: fused decode + bg + candidate filter.
// 256 threads = 4 waves per block, block owns 128 rows (amortizes the
// per-block fixed latency chain: stage-issue -> vmcnt(0) -> barrier ->
// atomic round-trips). Per-wave logic identical to R13 (proven): 32 rows x
// 2 lanes/row, union-pruned ballots, 2 alloc atomics, ranked scatter.
// ---------------------------------------------------------------------------
__global__ __launch_bounds__(256) void k_decode_filter(
    const float* __restrict__ deltas, const float* __restrict__ labels,
    const float* __restrict__ priors, float4* __restrict__ boxes,
    unsigned char* __restrict__ bg, int* __restrict__ cnt_g,
    u64* __restrict__ cand_g)
{
    __shared__ float4 lab4[2592];             // 128 rows x 81 floats
    __shared__ u64 s_mask[4][CC];
    __shared__ int s_base[4][CC];

    int tid = threadIdx.x;
    int w = tid >> 6, lane = tid & 63;
    int b = blockIdx.x / RB, blk = blockIdx.x - b * RB;
    int row0 = blk * 128;
    int rows = NN - row0; if (rows > 128) rows = 128;  // 128 or 116 (both %4==0)
    const float4* src = (const float4*)(labels + ((size_t)b * NN + row0) * CC);
    int nf4 = rows * CC / 4;                  // 2592 or 2349 (both integral)

    // async staging: 4 waves interleave over full 64-float4 chunks
    int nfull = nf4 >> 6;                     // 40 or 36
    for (int j = w; j < nfull; j += 4) {
        __builtin_amdgcn_global_load_lds(
            (const __attribute__((address_space(1))) void*)(src + (j << 6) + lane),
            (__attribute__((address_space(3))) void*)(lab4 + (j << 6)),
            16, 0, 0);
    }
    // remainder (32 or 45 float4): predicated copy by 256 threads
    int idx = (nfull << 6) + tid;
    bool hasrem = idx < nf4;
    float4 tv;
    if (hasrem) tv = src[idx];
    asm volatile("s_waitcnt vmcnt(0)" ::: "memory");
    if (hasrem) lab4[idx] = tv;
    __syncthreads();

    int row = lane & 31, h = lane >> 5;
    int rl = w * 32 + row;                    // row within block (0..127)
    bool inb = rl < rows;
    int n = row0 + rl;
    const float* L = (const float*)lab4 + rl * CC;

    int c0 = h ? 41 : 0, c1 = h ? 81 : 41;
    float L0 = L[0];
    float mq = L[c0];
    u64 win = 0;                              // own-half candidate bits (41/40)
    for (int c = c0; c < c1; ++c) {
        float v = L[c];
        mq = fmaxf(mq, v);
        float th = (c == 0) ? T1C0 : T1;
        if (v > th) win |= 1ull << (c - c0);
    }
    float rm = fmaxf(mq, __shfl_xor(mq, 32));
    bool isbg = (L0 >= rm);                   // argmax==0, first-index rule
    if (inb && h == 0) bg[(size_t)b * NN + n] = isbg ? 1 : 0;
    if (!inb || isbg) win = 0;

    // position window bits into the 81-bit class space
    u64 w0 = h ? (win << 41) : win;
    u32 w1 = h ? (u32)(win >> 23) : 0u;

    // phase 1a: wave-OR union of candidate classes (12 shfl-ORs)
    u64 u0 = w0; u32 u1 = w1;
    #pragma unroll
    for (int off = 1; off < 64; off <<= 1) {
        u0 |= __shfl_xor(u0, off);
        u1 |= __shfl_xor(u1, off);
    }

    // phase 1b: zero this wave's mask row (alloc phase reads all 81)
    s_mask[w][lane] = 0ull;
    if (lane < CC - 64) s_mask[w][64 + lane] = 0ull;

    // phase 1c: ballots ONLY for union classes (~7 instead of 81)
    u64 t0u = u0;
    while (t0u) {
        int c = __ffsll(t0u) - 1; t0u &= t0u - 1;
        u64 mm = __ballot((w0 >> c) & 1);
        if (lane == 0) s_mask[w][c] = mm;
    }
    u32 t1u = u1;
    while (t1u) {
        int j = __ffs(t1u) - 1; t1u &= t1u - 1;
        u64 mm = __ballot((w1 >> j) & 1);
        if (lane == 0) s_mask[w][64 + j] = mm;
    }

    // phase 2: 81 concurrent slot allocations per wave (2 atomic instrs)
    {
        u64 mk = s_mask[w][lane];
        int v2 = 0;
        if (mk) v2 = atomicAdd(&cnt_g[(b * CC + lane) * PADI], (int)__popcll(mk));
        s_base[w][lane] = v2;
        int c3 = 64 + lane;
        if (c3 < CC) {
            u64 mk3 = s_mask[w][c3];
            int v3 = 0;
            if (mk3) v3 = atomicAdd(&cnt_g[(b * CC + c3) * PADI], (int)__popcll(mk3));
            s_base[w][c3] = v3;
        }
    }

    // phase 3: ranked fire-and-forget scatter over own window bits
    u64 ltmask = (lane == 63) ? 0x7FFFFFFFFFFFFFFFull : ((1ull << lane) - 1ull);
    u64 wrem = win;
    while (wrem) {
        int j = __ffsll(wrem) - 1;
        wrem &= wrem - 1;
        int c = h * 41 + j;
        u64 mm = s_mask[w][c];
        int p = s_base[w][c] + (int)__popcll(mm & ltmask);
        if (p < CAND_CAP)
            cand_g[(size_t)(b * CC + c) * CAND_CAP + p] = pack_cand(L[c], n);
    }

    // box decode (exact numpy op order, FMA-free); h==0 lane per row
    if (inb && h == 0) {
        size_t r = (size_t)b * NN + n;
        float4 pr = ((const float4*)priors)[n];
        float ph  = __fsub_rn(pr.z, pr.x);
        float pw  = __fsub_rn(pr.w, pr.y);
        float pcy = __fadd_rn(pr.x, __fmul_rn(0.5f, ph));
        float pcx = __fadd_rn(pr.y, __fmul_rn(0.5f, pw));
        float4 dl = ((const float4*)deltas)[r];
        float d0 = __fmul_rn(dl.x, 0.1f);
        float d1 = __fmul_rn(dl.y, 0.1f);
        float d2 = __fmul_rn(dl.z, 0.2f);
        float d3 = __fmul_rn(dl.w, 0.2f);
        float cy = __fadd_rn(__fmul_rn(d0, ph), pcy);
        float cx = __fadd_rn(__fmul_rn(d1, pw), pcx);
        float hh = __fmul_rn(expf(d2), ph);
        float ww = __fmul_rn(expf(d3), pw);
        float h2 = __fmul_rn(hh, 0.5f);
        float w2 = __fmul_rn(ww, 0.5f);
        float y1 = fminf(fmaxf(__fsub_rn(cy, h2), 0.0f), 1.0f);
        float x1 = fminf(fmaxf(__fsub_rn(cx, w2), 0.0f), 1.0f);
        float y2 = fminf(fmaxf(__fadd_rn(cy, h2), 0.0f), 1.0f);
        float x2 = fminf(fmaxf(__fadd_rn(cx, w2), 0.0f), 1.0f);
        boxes[r] = make_float4(y1, x1, y2, x2);
    }
}

// ---------------------------------------------------------------------------
// Kernel 2: per-(b,c) sorted-scan greedy NMS. 256 threads. (unchanged)
// ---------------------------------------------------------------------------
__global__ __launch_bounds__(256) void k_nms(
    const float* __restrict__ labels, const unsigned char* __restrict__ bg,
    const float4* __restrict__ boxes, const int* __restrict__ cnt_g,
    const u64* __restrict__ cand_g,
    float* __restrict__ out_s, int* __restrict__ out_i)
{
    __shared__ u64 arr[CAND_CAP];
    __shared__ float4 sbox[CHUNK];
    __shared__ float ks[KK];
    __shared__ int   ki[KK];
    __shared__ int s_kept, s_cnt;

    int bc = blockIdx.x, tid = threadIdx.x;
    int b = bc / CC, c = bc - b * CC;
    float thrc = (c == 0) ? T1C0 : T1;
    const float4* bxb = boxes + (size_t)b * NN;

    int gcnt = cnt_g[bc * PADI];
    bool ovf = gcnt > CAND_CAP;
    int cnt0 = ovf ? 0 : gcnt;
    for (int i = tid; i < CAND_CAP; i += 256)
        arr[i] = (i < cnt0) ? cand_g[(size_t)bc * CAND_CAP + i] : 0ull;
    if (tid == 0) { s_kept = 0; s_cnt = cnt0; }
    __syncthreads();

    float4 kb = make_float4(0.f, 0.f, 0.f, 0.f);
    float  ka = 0.0f;
    float hi = ovf ? 1.0001f : thrc;
    float bw = TIER_W;
    bool first = !ovf;

    while (true) {
        if (!first) {
            if (s_kept >= KK || hi <= 0.5f) break;
            float lo = fmaxf(hi - bw, 0.5f);
            if (tid == 0) s_cnt = 0;
            __syncthreads();
            const float* lab = labels + (size_t)b * NN * CC + c;
            const unsigned char* bgb = bg + (size_t)b * NN;
            for (int n = tid; n < NN; n += 256) {
                float v = lab[(size_t)n * CC];
                if (v > lo && v <= hi && v > 0.5f && !bgb[n]) {
                    int p = atomicAdd(&s_cnt, 1);
                    if (p < CAND_CAP) arr[p] = pack_cand(v, n);
                }
            }
            __syncthreads();
            if (s_cnt > CAND_CAP && bw > 1e-7f) {  // band overflow: shrink, retry
                bw *= 0.5f;
                __syncthreads();
                continue;
            }
            int c2 = min(s_cnt, CAND_CAP);
            for (int i = tid; i < CAND_CAP; i += 256)
                if (i >= c2) arr[i] = 0ull;
            hi = lo;
            bw = TIER_W;
            __syncthreads();
        }
        first = false;

        int cs = min(s_cnt, CAND_CAP);
        if (cs <= 128)      bitonic_desc<128, 256>(arr, tid);  // uniform branch
        else if (cs <= 256) bitonic_desc<256, 256>(arr, tid);
        else                bitonic_desc<CAND_CAP, 256>(arr, tid);

        // chunked stage + scan: most blocks finish in the first 128
        for (int ch0 = 0; ch0 < cs; ch0 += CHUNK) {
            if (s_kept >= KK) break;                       // uniform (post-sync)
            int che = min(ch0 + CHUNK, cs);
            for (int i = ch0 + tid; i < che; i += 256) {
                int n = (int)(~(u32)arr[i]);
                if ((u32)n < (u32)NN) sbox[i - ch0] = bxb[n];  // guarded
            }
            __syncthreads();
            if (tid < 64) {                    // wave 0: serial greedy scan
                int kept = s_kept;
                for (int i = ch0; i < che; ++i) {
                    u64 key = arr[i];
                    float sc = __uint_as_float((u32)(key >> 32));
                    int n = (int)(~(u32)key);
                    float4 cb = sbox[i - ch0];
                    float a1 = __fmul_rn(__fsub_rn(cb.z, cb.x), __fsub_rn(cb.w, cb.y));
                    bool sup = false;
                    if (tid < kept) {
                        float iy1 = fmaxf(kb.x, cb.x);
                        float ix1 = fmaxf(kb.y, cb.y);
                        float iy2 = fminf(kb.z, cb.z);
                        float ix2 = fminf(kb.w, cb.w);
                        float ih = fmaxf(__fsub_rn(iy2, iy1), 0.0f);
                        float iw = fmaxf(__fsub_rn(ix2, ix1), 0.0f);
                        float inter = __fmul_rn(ih, iw);
                        float den = __fadd_rn(__fsub_rn(__fadd_rn(ka, a1), inter), 1e-8f);
                        sup = __fdiv_rn(inter, den) > 0.5f;
                    }
                    if (__ballot(sup) == 0ull) {
                        if (tid == kept) { kb = cb; ka = a1; }
                        if (tid == 0)    { ks[kept] = sc; ki[kept] = n; }
                        ++kept;
                        if (kept == KK) break;
                    }
                }
                if (tid == 0) s_kept = kept;
            }
            __syncthreads();
        }
    }

    int kept = min(s_kept, KK);
    for (int k = tid; k < KK; k += 256) {
        out_s[(size_t)bc * KK + k] = (k < kept) ? ks[k] : 0.0f;
        out_i[(size_t)bc * KK + k] = (k < kept) ? ki[k] : 0;
    }
}

// ---------------------------------------------------------------------------
// Kernel 3: per-batch bitonic top-200 (stable) + output assembly.
// (R2-R5-proven single-kernel structure; replaces topk1+topk2.)
// ---------------------------------------------------------------------------
__global__ __launch_bounds__(1024) void k_topk(
    const float* __restrict__ nms_s, const int* __restrict__ nms_i,
    const float4* __restrict__ boxes, float* __restrict__ out)
{
    __shared__ u64 arr[4096];
    __shared__ int s_vc;
    int b = blockIdx.x, tid = threadIdx.x;
    for (int i = tid; i < 4096; i += 1024) {
        u64 v = 0ull;
        if (i < CC * KK) {
            float s = nms_s[(size_t)b * CC * KK + i];
            v = ((u64)__float_as_uint(s) << 32) | (u32)(~(u32)i);
        }
        arr[i] = v;
    }
    if (tid == 0) s_vc = 0;
    __syncthreads();

    bitonic_desc<4096, 1024>(arr, tid);

    if (tid < MT) {
        u64 key = arr[tid];
        float sc = __uint_as_float((u32)(key >> 32));
        int fp = (int)(~(u32)key);
        bool valid = sc > 0.0f;
        float4 bb = make_float4(0.f, 0.f, 0.f, 0.f);
        float cls = 0.0f;
        if (valid) {
            int aidx = nms_i[(size_t)b * CC * KK + fp];
            bb = boxes[(size_t)b * NN + aidx];
            cls = (float)(fp / KK);
        }
        ((float4*)out)[(size_t)b * MT + tid] = bb;
        out[(size_t)BB * MT * 4 + (size_t)b * MT + tid] = sc;
        out[(size_t)BB * MT * 5 + (size_t)b * MT + tid] = cls;
        if (valid) atomicAdd(&s_vc, 1);
    }
    __syncthreads();
    if (tid == 0) out[(size_t)BB * MT * 6 + b] = (float)s_vc;
}

// ---------------------------------------------------------------------------
extern "C" void kernel_launch(void* const* d_in, const int* in_sizes, int n_in,
                              void* d_out, int out_size, void* d_ws, size_t ws_size,
                              hipStream_t stream)
{
    const float* deltas = (const float*)d_in[0];
    const float* labels = (const float*)d_in[1];
    const float* priors = (const float*)d_in[2];
    float* out = (float*)d_out;

    char* ws = (char*)d_ws;
    size_t off = 0;
    float4* boxes = (float4*)(ws + off);            off += (size_t)NROWS * 16;
    unsigned char* bg = (unsigned char*)(ws + off); off += ((size_t)NROWS + 127) & ~127ull;
    int* cnt_g = (int*)(ws + off);                  off += (size_t)BB * CC * PADI * 4;
    u64* cand_g = (u64*)(ws + off);                 off += (size_t)BB * CC * CAND_CAP * 8;
    float* nms_s = (float*)(ws + off);              off += (size_t)BB * CC * KK * 4;
    int* nms_i = (int*)(ws + off);                  off += (size_t)BB * CC * KK * 4;

    k_zero<<<(BB * CC + 255) / 256, 256, 0, stream>>>(cnt_g);
    k_decode_filter<<<BB * RB, 256, 0, stream>>>(deltas, labels, priors,
                                                 boxes, bg, cnt_g, cand_g);
    k_nms<<<BB * CC, 256, 0, stream>>>(labels, bg, boxes, cnt_g, cand_g, nms_s, nms_i);
    k_topk<<<BB, 1024, 0, stream>>>(nms_s, nms_i, boxes, out);
}

// Round 15
// 136.575 us; speedup vs baseline: 1.0666x; 1.0666x over previous
//
#include <hip/hip_runtime.h>
#include <math.h>

#define BB 16
#define NN 24564
#define CC 81
#define KK 50
#define MT 200
#define NROWS (BB * NN)
#define RB 384                 // row-blocks per batch: ceil(24564/64)
#define CAND_CAP 512           // class c>0: ~123+-11 (35 sigma); class 0: ~389+-20 (6 sigma)
#define T1 0.995f              // tier-1 threshold, classes 1..80
#define T1C0 0.975f            // tier-1 threshold, class 0 (masked-column yield is lower)
#define TIER_W 0.02f
#define PADI 32                // ints per counter slot (128B padding)
#define CHUNK 128              // k_nms box-staging chunk

typedef unsigned long long u64;
typedef unsigned int u32;

__device__ __forceinline__ u64 pack_cand(float s, int n) {
    return ((u64)__float_as_uint(s) << 32) | (u32)(~(u32)n);
}

// descending bitonic sort of P u64 keys in LDS, NT threads
template <int P, int NT>
__device__ __forceinline__ void bitonic_desc(u64* a, int tid) {
    for (int k = 2; k <= P; k <<= 1) {
        for (int j = k >> 1; j > 0; j >>= 1) {
            for (int i = tid; i < P; i += NT) {
                int l = i ^ j;
                if (l > i) {
                    u64 x = a[i], y = a[l];
                    bool sw = (i & k) ? (x > y) : (x < y);
                    if (sw) { a[i] = y; a[l] = x; }
                }
            }
            __syncthreads();
        }
    }
}

// ---------------------------------------------------------------------------
// Kernel 0: zero the 1296 used counter slots.
// ---------------------------------------------------------------------------
__global__ __launch_bounds__(256) void k_zero(int* __restrict__ cnt_g)
{
    int i = blockIdx.x * 256 + threadIdx.x;
    if (i < BB * CC) cnt_g[i * PADI] = 0;
}

// ---------------------------------------------------------------------------
// Kernel 1: fused decode + bg + candidate filter.  (R13-proven structure:
// 64 rows/block, 2 waves, 2 lanes/row, union-pruned ballots.)
// R15 change: priors/deltas epilogue loads issued EARLY (before the vmcnt(0)
// drain) so their latency hides under the staging drain (T14 pattern).
// ---------------------------------------------------------------------------
__global__ __launch_bounds__(128) void k_decode_filter(
    const float* __restrict__ deltas, const float* __restrict__ labels,
    const float* __restrict__ priors, float4* __restrict__ boxes,
    unsigned char* __restrict__ bg, int* __restrict__ cnt_g,
    u64* __restrict__ cand_g)
{
    __shared__ float4 lab4[1296];             // 64 rows x 81 floats
    __shared__ u64 s_mask[2][CC];
    __shared__ int s_base[2][CC];

    int tid = threadIdx.x;
    int w = tid >> 6, lane = tid & 63;
    int b = blockIdx.x / RB, blk = blockIdx.x - b * RB;
    int row0 = blk * 64;
    int rows = NN - row0; if (rows > 64) rows = 64;   // 64 or 52
    const float4* src = (const float4*)(labels + ((size_t)b * NN + row0) * CC);
    int nf4 = rows * CC / 4;                  // 1296 or 1053 (both integral)

    // async staging: waves interleave over full 64-float4 chunks
    int nfull = nf4 >> 6;                     // 20 or 16
    for (int j = w; j < nfull; j += 2) {
        __builtin_amdgcn_global_load_lds(
            (const __attribute__((address_space(1))) void*)(src + (j << 6) + lane),
            (__attribute__((address_space(3))) void*)(lab4 + (j << 6)),
            16, 0, 0);
    }
    // remainder (16 or 29 float4): predicated copy by 128 threads
    int idx = (nfull << 6) + tid;
    bool hasrem = idx < nf4;
    float4 tv;
    if (hasrem) tv = src[idx];

    // EARLY epilogue prefetch (issued before the drain; latency overlapped)
    int row = lane & 31, h = lane >> 5;
    int rl = w * 32 + row;                    // row within block
    bool inb = rl < rows;
    int n = row0 + rl;
    float4 pr, dl;
    if (inb && h == 0) {
        pr = ((const float4*)priors)[n];
        dl = ((const float4*)deltas)[(size_t)b * NN + n];
    }

    asm volatile("s_waitcnt vmcnt(0)" ::: "memory");
    if (hasrem) lab4[idx] = tv;
    __syncthreads();

    const float* L = (const float*)lab4 + rl * CC;

    int c0 = h ? 41 : 0, c1 = h ? 81 : 41;
    float L0 = L[0];
    float mq = L[c0];
    u64 win = 0;                              // own-half candidate bits (41/40)
    for (int c = c0; c < c1; ++c) {
        float v = L[c];
        mq = fmaxf(mq, v);
        float th = (c == 0) ? T1C0 : T1;
        if (v > th) win |= 1ull << (c - c0);
    }
    float rm = fmaxf(mq, __shfl_xor(mq, 32));
    bool isbg = (L0 >= rm);                   // argmax==0, first-index rule
    if (inb && h == 0) bg[(size_t)b * NN + n] = isbg ? 1 : 0;
    if (!inb || isbg) win = 0;

    // position window bits into the 81-bit class space
    u64 w0 = h ? (win << 41) : win;
    u32 w1 = h ? (u32)(win >> 23) : 0u;

    // phase 1a: wave-OR union of candidate classes (12 shfl-ORs)
    u64 u0 = w0; u32 u1 = w1;
    #pragma unroll
    for (int off = 1; off < 64; off <<= 1) {
        u0 |= __shfl_xor(u0, off);
        u1 |= __shfl_xor(u1, off);
    }

    // phase 1b: zero this wave's mask row (alloc phase reads all 81)
    s_mask[w][lane] = 0ull;
    if (lane < CC - 64) s_mask[w][64 + lane] = 0ull;

    // phase 1c: ballots ONLY for union classes (~7 instead of 81)
    u64 t0u = u0;
    while (t0u) {
        int c = __ffsll(t0u) - 1; t0u &= t0u - 1;
        u64 mm = __ballot((w0 >> c) & 1);
        if (lane == 0) s_mask[w][c] = mm;
    }
    u32 t1u = u1;
    while (t1u) {
        int j = __ffs(t1u) - 1; t1u &= t1u - 1;
        u64 mm = __ballot((w1 >> j) & 1);
        if (lane == 0) s_mask[w][64 + j] = mm;
    }

    // phase 2: 81 concurrent slot allocations per wave (2 atomic instrs)
    {
        u64 mk = s_mask[w][lane];
        int v2 = 0;
        if (mk) v2 = atomicAdd(&cnt_g[(b * CC + lane) * PADI], (int)__popcll(mk));
        s_base[w][lane] = v2;
        int c3 = 64 + lane;
        if (c3 < CC) {
            u64 mk3 = s_mask[w][c3];
            int v3 = 0;
            if (mk3) v3 = atomicAdd(&cnt_g[(b * CC + c3) * PADI], (int)__popcll(mk3));
            s_base[w][c3] = v3;
        }
    }

    // phase 3: ranked fire-and-forget scatter over own window bits
    u64 ltmask = (lane == 63) ? 0x7FFFFFFFFFFFFFFFull : ((1ull << lane) - 1ull);
    u64 wrem = win;
    while (wrem) {
        int j = __ffsll(wrem) - 1;
        wrem &= wrem - 1;
        int c = h * 41 + j;
        u64 mm = s_mask[w][c];
        int p = s_base[w][c] + (int)__popcll(mm & ltmask);
        if (p < CAND_CAP)
            cand_g[(size_t)(b * CC + c) * CAND_CAP + p] = pack_cand(L[c], n);
    }

    // box decode (exact numpy op order, FMA-free); h==0 lane per row
    // pr/dl already in registers (prefetched before the drain)
    if (inb && h == 0) {
        size_t r = (size_t)b * NN + n;
        float ph  = __fsub_rn(pr.z, pr.x);
        float pw  = __fsub_rn(pr.w, pr.y);
        float pcy = __fadd_rn(pr.x, __fmul_rn(0.5f, ph));
        float pcx = __fadd_rn(pr.y, __fmul_rn(0.5f, pw));
        float d0 = __fmul_rn(dl.x, 0.1f);
        float d1 = __fmul_rn(dl.y, 0.1f);
        float d2 = __fmul_rn(dl.z, 0.2f);
        float d3 = __fmul_rn(dl.w, 0.2f);
        float cy = __fadd_rn(__fmul_rn(d0, ph), pcy);
        float cx = __fadd_rn(__fmul_rn(d1, pw), pcx);
        float hh = __fmul_rn(expf(d2), ph);
        float ww = __fmul_rn(expf(d3), pw);
        float h2 = __fmul_rn(hh, 0.5f);
        float w2 = __fmul_rn(ww, 0.5f);
        float y1 = fminf(fmaxf(__fsub_rn(cy, h2), 0.0f), 1.0f);
        float x1 = fminf(fmaxf(__fsub_rn(cx, w2), 0.0f), 1.0f);
        float y2 = fminf(fmaxf(__fadd_rn(cy, h2), 0.0f), 1.0f);
        float x2 = fminf(fmaxf(__fadd_rn(cx, w2), 0.0f), 1.0f);
        boxes[r] = make_float4(y1, x1, y2, x2);
    }
}

// ---------------------------------------------------------------------------
// Kernel 2: per-(b,c) sorted-scan greedy NMS. 256 threads. (unchanged)
// ---------------------------------------------------------------------------
__global__ __launch_bounds__(256) void k_nms(
    const float* __restrict__ labels, const unsigned char* __restrict__ bg,
    const float4* __restrict__ boxes, const int* __restrict__ cnt_g,
    const u64* __restrict__ cand_g,
    float* __restrict__ out_s, int* __restrict__ out_i)
{
    __shared__ u64 arr[CAND_CAP];
    __shared__ float4 sbox[CHUNK];
    __shared__ float ks[KK];
    __shared__ int   ki[KK];
    __shared__ int s_kept, s_cnt;

    int bc = blockIdx.x, tid = threadIdx.x;
    int b = bc / CC, c = bc - b * CC;
    float thrc = (c == 0) ? T1C0 : T1;
    const float4* bxb = boxes + (size_t)b * NN;

    int gcnt = cnt_g[bc * PADI];
    bool ovf = gcnt > CAND_CAP;
    int cnt0 = ovf ? 0 : gcnt;
    for (int i = tid; i < CAND_CAP; i += 256)
        arr[i] = (i < cnt0) ? cand_g[(size_t)bc * CAND_CAP + i] : 0ull;
    if (tid == 0) { s_kept = 0; s_cnt = cnt0; }
    __syncthreads();

    float4 kb = make_float4(0.f, 0.f, 0.f, 0.f);
    float  ka = 0.0f;
    float hi = ovf ? 1.0001f : thrc;
    float bw = TIER_W;
    bool first = !ovf;

    while (true) {
        if (!first) {
            if (s_kept >= KK || hi <= 0.5f) break;
            float lo = fmaxf(hi - bw, 0.5f);
            if (tid == 0) s_cnt = 0;
            __syncthreads();
            const float* lab = labels + (size_t)b * NN * CC + c;
            const unsigned char* bgb = bg + (size_t)b * NN;
            for (int n = tid; n < NN; n += 256) {
                float v = lab[(size_t)n * CC];
                if (v > lo && v <= hi && v > 0.5f && !bgb[n]) {
                    int p = atomicAdd(&s_cnt, 1);
                    if (p < CAND_CAP) arr[p] = pack_cand(v, n);
                }
            }
            __syncthreads();
            if (s_cnt > CAND_CAP && bw > 1e-7f) {  // band overflow: shrink, retry
                bw *= 0.5f;
                __syncthreads();
                continue;
            }
            int c2 = min(s_cnt, CAND_CAP);
            for (int i = tid; i < CAND_CAP; i += 256)
                if (i >= c2) arr[i] = 0ull;
            hi = lo;
            bw = TIER_W;
            __syncthreads();
        }
        first = false;

        int cs = min(s_cnt, CAND_CAP);
        if (cs <= 128)      bitonic_desc<128, 256>(arr, tid);  // uniform branch
        else if (cs <= 256) bitonic_desc<256, 256>(arr, tid);
        else                bitonic_desc<CAND_CAP, 256>(arr, tid);

        // chunked stage + scan: most blocks finish in the first 128
        for (int ch0 = 0; ch0 < cs; ch0 += CHUNK) {
            if (s_kept >= KK) break;                       // uniform (post-sync)
            int che = min(ch0 + CHUNK, cs);
            for (int i = ch0 + tid; i < che; i += 256) {
                int n = (int)(~(u32)arr[i]);
                if ((u32)n < (u32)NN) sbox[i - ch0] = bxb[n];  // guarded
            }
            __syncthreads();
            if (tid < 64) {                    // wave 0: serial greedy scan
                int kept = s_kept;
                for (int i = ch0; i < che; ++i) {
                    u64 key = arr[i];
                    float sc = __uint_as_float((u32)(key >> 32));
                    int n = (int)(~(u32)key);
                    float4 cb = sbox[i - ch0];
                    float a1 = __fmul_rn(__fsub_rn(cb.z, cb.x), __fsub_rn(cb.w, cb.y));
                    bool sup = false;
                    if (tid < kept) {
                        float iy1 = fmaxf(kb.x, cb.x);
                        float ix1 = fmaxf(kb.y, cb.y);
                        float iy2 = fminf(kb.z, cb.z);
                        float ix2 = fminf(kb.w, cb.w);
                        float ih = fmaxf(__fsub_rn(iy2, iy1), 0.0f);
                        float iw = fmaxf(__fsub_rn(ix2, ix1), 0.0f);
                        float inter = __fmul_rn(ih, iw);
                        float den = __fadd_rn(__fsub_rn(__fadd_rn(ka, a1), inter), 1e-8f);
                        sup = __fdiv_rn(inter, den) > 0.5f;
                    }
                    if (__ballot(sup) == 0ull) {
                        if (tid == kept) { kb = cb; ka = a1; }
                        if (tid == 0)    { ks[kept] = sc; ki[kept] = n; }
                        ++kept;
                        if (kept == KK) break;
                    }
                }
                if (tid == 0) s_kept = kept;
            }
            __syncthreads();
        }
    }

    int kept = min(s_kept, KK);
    for (int k = tid; k < KK; k += 256) {
        out_s[(size_t)bc * KK + k] = (k < kept) ? ks[k] : 0.0f;
        out_i[(size_t)bc * KK + k] = (k < kept) ? ki[k] : 0;
    }
}

// ---------------------------------------------------------------------------
// Kernel 3a: per-(batch, 512-chunk) partial top-200. Grid = BB*8 blocks.
// ---------------------------------------------------------------------------
__global__ __launch_bounds__(256) void k_topk1(
    const float* __restrict__ nms_s, u64* __restrict__ topA)
{
    __shared__ u64 arr[512];
    int bchunk = blockIdx.x;
    int b = bchunk >> 3, ch = bchunk & 7;
    int tid = threadIdx.x;
    int base = ch * 512;
    for (int i = tid; i < 512; i += 256) {
        int fp = base + i;
        u64 v = 0ull;
        if (fp < CC * KK) {
            float s = nms_s[(size_t)b * CC * KK + fp];
            v = ((u64)__float_as_uint(s) << 32) | (u32)(~(u32)fp);
        }
        arr[i] = v;
    }
    __syncthreads();
    bitonic_desc<512, 256>(arr, tid);
    if (tid < MT) topA[(size_t)bchunk * MT + tid] = arr[tid];
}

// ---------------------------------------------------------------------------
// Kernel 3b: per-batch merge of 8x200 -> stable top-200 + output assembly.
// ---------------------------------------------------------------------------
__global__ __launch_bounds__(512) void k_topk2(
    const u64* __restrict__ topA, const int* __restrict__ nms_i,
    const float4* __restrict__ boxes, float* __restrict__ out)
{
    __shared__ u64 arr[2048];
    __shared__ int s_vc;
    int b = blockIdx.x, tid = threadIdx.x;
    for (int i = tid; i < 2048; i += 512)
        arr[i] = (i < 8 * MT) ? topA[(size_t)b * 8 * MT + i] : 0ull;
    if (tid == 0) s_vc = 0;
    __syncthreads();

    bitonic_desc<2048, 512>(arr, tid);

    if (tid < MT) {
        u64 key = arr[tid];
        float sc = __uint_as_float((u32)(key >> 32));
        int fp = (int)(~(u32)key);
        bool valid = sc > 0.0f;
        float4 bb = make_float4(0.f, 0.f, 0.f, 0.f);
        float cls = 0.0f;
        if (valid) {
            int aidx = nms_i[(size_t)b * CC * KK + fp];
            bb = boxes[(size_t)b * NN + aidx];
            cls = (float)(fp / KK);
        }
        ((float4*)out)[(size_t)b * MT + tid] = bb;
        out[(size_t)BB * MT * 4 + (size_t)b * MT + tid] = sc;
        out[(size_t)BB * MT * 5 + (size_t)b * MT + tid] = cls;
        if (valid) atomicAdd(&s_vc, 1);
    }
    __syncthreads();
    if (tid == 0) out[(size_t)BB * MT * 6 + b] = (float)s_vc;
}

// ---------------------------------------------------------------------------
extern "C" void kernel_launch(void* const* d_in, const int* in_sizes, int n_in,
                              void* d_out, int out_size, void* d_ws, size_t ws_size,
                              hipStream_t stream)
{
    const float* deltas = (const float*)d_in[0];
    const float* labels = (const float*)d_in[1];
    const float* priors = (const float*)d_in[2];
    float* out = (float*)d_out;

    char* ws = (char*)d_ws;
    size_t off = 0;
    float4* boxes = (float4*)(ws + off);            off += (size_t)NROWS * 16;
    unsigned char* bg = (unsigned char*)(ws + off); off += ((size_t)NROWS + 127) & ~127ull;
    int* cnt_g = (int*)(ws + off);                  off += (size_t)BB * CC * PADI * 4;
    u64* cand_g = (u64*)(ws + off);                 off += (size_t)BB * CC * CAND_CAP * 8;
    float* nms_s = (float*)(ws + off);              off += (size_t)BB * CC * KK * 4;
    int* nms_i = (int*)(ws + off);                  off += (size_t)BB * CC * KK * 4;
    u64* topA = (u64*)(ws + off);                   off += (size_t)BB * 8 * MT * 8;

    k_zero<<<(BB * CC + 255) / 256, 256, 0, stream>>>(cnt_g);
    k_decode_filter<<<BB * RB, 128, 0, stream>>>(deltas, labels, priors,
                                                 boxes, bg, cnt_g, cand_g);
    k_nms<<<BB * CC, 256, 0, stream>>>(labels, bg, boxes, cnt_g, cand_g, nms_s, nms_i);
    k_topk1<<<BB * 8, 256, 0, stream>>>(nms_s, topA);
    k_topk2<<<BB, 512, 0, stream>>>(topA, nms_i, boxes, out);
}